// Round 2
// baseline (130.058 us; speedup 1.0000x reference)
//
#include <hip/hip_runtime.h>
#include <hip/hip_bf16.h>

#define SQ 2048
#define NH 32
#define DH 128
#define NK 256
#define SCALE 0.08838834764831845f
#define LOG2E 1.4426950408889634f

typedef __attribute__((ext_vector_type(8))) __bf16 bf16x8;
typedef __attribute__((ext_vector_type(4))) float floatx4;

// element strides (u16)
#define VB_STRIDE 72    // V transposed [d][k_local]; 144 B rows
#define PB_STRIDE 264   // P [head][col]; 528 B rows

// LDS layout (bytes): pbuf 16896 | vbuf 18432 | red 512 | red2 512
#define OFF_VB   16896
#define OFF_RED  35328
#define OFF_RED2 35840
#define SMEM_SZ  36352   // 4 blocks/CU (4 x 36352 = 145408 <= 163840)

__device__ __forceinline__ unsigned pk_bf16(float a, float b) {
  // v_cvt_pk_bf16_f32 (RNE), packs two fp32 -> one dword of 2 bf16
  union { __hip_bfloat162 h2; unsigned u; } c;
  c.h2 = __float22bfloat162_rn(make_float2(a, b));
  return c.u;
}

__device__ __forceinline__ float fast_exp2(float x) {
#if __has_builtin(__builtin_amdgcn_exp2f)
  return __builtin_amdgcn_exp2f(x);
#else
  return exp2f(x);
#endif
}

// rotate within rows of 16 lanes (VALU DPP — keeps reductions off the LDS pipe)
template <int CTRL>
__device__ __forceinline__ float dpp_rot(float x) {
  int i = __builtin_bit_cast(int, x);
  i = __builtin_amdgcn_mov_dpp(i, CTRL, 0xF, 0xF, true);
  return __builtin_bit_cast(float, i);
}
#define RED16_MAX(v) { v = fmaxf(v, dpp_rot<0x121>(v)); v = fmaxf(v, dpp_rot<0x122>(v)); \
                       v = fmaxf(v, dpp_rot<0x124>(v)); v = fmaxf(v, dpp_rot<0x128>(v)); }
#define RED16_SUM(v) { v += dpp_rot<0x121>(v); v += dpp_rot<0x122>(v); \
                       v += dpp_rot<0x124>(v); v += dpp_rot<0x128>(v); }

// ---- pre-pass: kv fp32 [4096][2][128] -> bf16 in d_ws ----
__global__ __launch_bounds__(256) void kv_to_bf16(const float* __restrict__ kv,
                                                  unsigned short* __restrict__ kvb) {
  int i = blockIdx.x * 256 + threadIdx.x;  // float4 index, 262144 total
  float4 f = ((const float4*)kv)[i];
  uint2 o = { pk_bf16(f.x, f.y), pk_bf16(f.z, f.w) };
  ((uint2*)kvb)[i] = o;
}

struct VR { uint4 a, b, c, d; };

__device__ __forceinline__ VR v_load(const unsigned short* __restrict__ kvb,
                                     const int* __restrict__ tkg, int c, int tid) {
  int rg = tid & 15, dg = tid >> 4;
  int r0 = rg * 4, d0 = dg * 8;
  int4 i4 = *(const int4*)&tkg[c * 64 + r0];
  VR v;
  v.a = *(const uint4*)(kvb + (size_t)i4.x * 256 + 128 + d0);
  v.b = *(const uint4*)(kvb + (size_t)i4.y * 256 + 128 + d0);
  v.c = *(const uint4*)(kvb + (size_t)i4.z * 256 + 128 + d0);
  v.d = *(const uint4*)(kvb + (size_t)i4.w * 256 + 128 + d0);
  return v;
}

__device__ __forceinline__ void v_write(unsigned short* vbuf, const VR& v, int tid) {
  int rg = tid & 15, dg = tid >> 4;
  int r0 = rg * 4, d0 = dg * 8;
  const unsigned* pa = (const unsigned*)&v.a;
  const unsigned* pb = (const unsigned*)&v.b;
  const unsigned* pc = (const unsigned*)&v.c;
  const unsigned* pd = (const unsigned*)&v.d;
#pragma unroll
  for (int w = 0; w < 4; w++) {
    unsigned lo01 = __builtin_amdgcn_perm(pb[w], pa[w], 0x05040100u);
    unsigned lo23 = __builtin_amdgcn_perm(pd[w], pc[w], 0x05040100u);
    unsigned hi01 = __builtin_amdgcn_perm(pb[w], pa[w], 0x07060302u);
    unsigned hi23 = __builtin_amdgcn_perm(pd[w], pc[w], 0x07060302u);
    uint2 lo = { lo01, lo23 }, hi = { hi01, hi23 };
    *(uint2*)&vbuf[(d0 + 2 * w) * VB_STRIDE + r0] = lo;
    *(uint2*)&vbuf[(d0 + 2 * w + 1) * VB_STRIDE + r0] = hi;
  }
}

// K B-fragments for one 64-key chunk: lane (quad,l16) covers key=idx (per-lane),
// 16B at d = ks*32 + quad*8. Loaded into NAMED registers 1-2 chunks ahead of use
// so the L2 gather latency hides under MFMA of the previous chunk(s).
struct KB { bf16x8 b[4]; };

__device__ __forceinline__ KB kb_load(const unsigned short* __restrict__ kvb,
                                      int idx, int quad) {
  const unsigned short* kp = kvb + (size_t)idx * 256 + quad * 8;
  KB k;
#pragma unroll
  for (int ks = 0; ks < 4; ks++) k.b[ks] = *(const bf16x8*)(kp + ks * 32);
  return k;
}

__device__ __forceinline__ void gemm_reg(const KB& kb, const bf16x8 af[2][4],
                                         floatx4& a0, floatx4& a1) {
  a0 = (floatx4){0.f, 0.f, 0.f, 0.f};
  a1 = (floatx4){0.f, 0.f, 0.f, 0.f};
  __builtin_amdgcn_s_setprio(1);
#pragma unroll
  for (int ks = 0; ks < 4; ks++) {
    a0 = __builtin_amdgcn_mfma_f32_16x16x32_bf16(af[0][ks], kb.b[ks], a0, 0, 0, 0);
    a1 = __builtin_amdgcn_mfma_f32_16x16x32_bf16(af[1][ks], kb.b[ks], a1, 0, 0, 0);
  }
  __builtin_amdgcn_s_setprio(0);
}

__device__ __forceinline__ void pv_chunk(const unsigned short* pbuf,
                                         const unsigned short* vbuf, int c,
                                         int wave, int quad, int l16,
                                         floatx4 oacc[2][2]) {
  __builtin_amdgcn_s_setprio(1);
#pragma unroll
  for (int ks = 0; ks < 2; ks++) {
    int kof = c * 64 + ks * 32 + quad * 8;
    bf16x8 a0 = *(const bf16x8*)&pbuf[l16 * PB_STRIDE + kof];
    bf16x8 a1 = *(const bf16x8*)&pbuf[(16 + l16) * PB_STRIDE + kof];
    int kl = ks * 32 + quad * 8;
    bf16x8 b0 = *(const bf16x8*)&vbuf[(wave * 32 + l16) * VB_STRIDE + kl];
    bf16x8 b1 = *(const bf16x8*)&vbuf[(wave * 32 + 16 + l16) * VB_STRIDE + kl];
    oacc[0][0] = __builtin_amdgcn_mfma_f32_16x16x32_bf16(a0, b0, oacc[0][0], 0, 0, 0);
    oacc[0][1] = __builtin_amdgcn_mfma_f32_16x16x32_bf16(a0, b1, oacc[0][1], 0, 0, 0);
    oacc[1][0] = __builtin_amdgcn_mfma_f32_16x16x32_bf16(a1, b0, oacc[1][0], 0, 0, 0);
    oacc[1][1] = __builtin_amdgcn_mfma_f32_16x16x32_bf16(a1, b1, oacc[1][1], 0, 0, 0);
  }
  __builtin_amdgcn_s_setprio(0);
}

__global__ __launch_bounds__(256, 4) void sparse_attn_kernel(
    const float* __restrict__ q, const unsigned short* __restrict__ kvb,
    const float* __restrict__ sink, const int* __restrict__ topk,
    float* __restrict__ out) {
  __shared__ __align__(16) char smem[SMEM_SZ];
  unsigned short* pbuf = (unsigned short*)smem;             // P [32][264]
  unsigned short* vbuf = (unsigned short*)(smem + OFF_VB);  // V^T chunk [128][72]
  float* red  = (float*)(smem + OFF_RED);
  float* red2 = (float*)(smem + OFF_RED2);

  const int tid = threadIdx.x;
  const int s = blockIdx.x;
  const int wave = tid >> 6;
  const int lane = tid & 63;
  const int quad = lane >> 4;
  const int l16 = lane & 15;
  const int* tkg = topk + (size_t)s * NK;

  // ---- Q loads first (independent of topk): 8x b128 per lane ----
  const float QSC = SCALE * LOG2E;
  const float* qp = q + (size_t)s * (NH * DH);
  float4 qf[2][4][2];
#pragma unroll
  for (int mt = 0; mt < 2; mt++)
#pragma unroll
    for (int ks = 0; ks < 4; ks++) {
      const float* base = qp + (mt * 16 + l16) * DH + ks * 32 + quad * 8;
      qf[mt][ks][0] = ((const float4*)base)[0];
      qf[mt][ks][1] = ((const float4*)base)[1];
    }

  // ---- per-lane topk columns for GEMM1 ----
  int kidx[4];
#pragma unroll
  for (int c = 0; c < 4; c++) kidx[c] = tkg[c * 64 + wave * 16 + l16];

  // ---- issue gathers 1-2 chunks ahead: K0, K1, V0 in flight now ----
  KB b0 = kb_load(kvb, kidx[0], quad);
  KB b1 = kb_load(kvb, kidx[1], quad);
  VR v0 = v_load(kvb, tkg, 0, tid);

  // sink -> regs
  float snk[2][4];
#pragma unroll
  for (int mt = 0; mt < 2; mt++)
#pragma unroll
    for (int r = 0; r < 4; r++)
      snk[mt][r] = sink[mt * 16 + quad * 4 + r] * LOG2E;

  // Q -> bf16 A-frags (VALU work overlaps the in-flight gathers)
  bf16x8 afrag[2][4];
#pragma unroll
  for (int mt = 0; mt < 2; mt++)
#pragma unroll
    for (int ks = 0; ks < 4; ks++) {
      float4 f0 = qf[mt][ks][0], f1 = qf[mt][ks][1];
      uint4 u = { pk_bf16(f0.x * QSC, f0.y * QSC), pk_bf16(f0.z * QSC, f0.w * QSC),
                  pk_bf16(f1.x * QSC, f1.y * QSC), pk_bf16(f1.z * QSC, f1.w * QSC) };
      afrag[mt][ks] = __builtin_bit_cast(bf16x8, u);
    }

  // ---- Phase 1: GEMM1, barrier-free, 2-deep register pipeline ----
  floatx4 sc[4][2];
  gemm_reg(b0, afrag, sc[0][0], sc[0][1]);
  KB b2 = kb_load(kvb, kidx[2], quad);
  v_write(vbuf, v0, tid);                 // vbuf unread until post-softmax barrier
  gemm_reg(b1, afrag, sc[1][0], sc[1][1]);
  KB b3 = kb_load(kvb, kidx[3], quad);
  gemm_reg(b2, afrag, sc[2][0], sc[2][1]);
  VR v1 = v_load(kvb, tkg, 1, tid);       // consumed after pv0: ~3 phases of cover
  gemm_reg(b3, afrag, sc[3][0], sc[3][1]);

  // ---- Phase 2: softmax with sink (scores in exp2 domain) ----
  float mh[2][4];
#pragma unroll
  for (int mt = 0; mt < 2; mt++)
#pragma unroll
    for (int r = 0; r < 4; r++) {
      float v = fmaxf(fmaxf(sc[0][mt][r], sc[1][mt][r]),
                      fmaxf(sc[2][mt][r], sc[3][mt][r]));
      RED16_MAX(v);
      mh[mt][r] = v;
    }
  if (l16 == 0) {
#pragma unroll
    for (int mt = 0; mt < 2; mt++)
#pragma unroll
      for (int r = 0; r < 4; r++)
        red[wave * 32 + mt * 16 + quad * 4 + r] = mh[mt][r];
  }
  __syncthreads();  // red visible
  VR v2 = v_load(kvb, tkg, 2, tid);       // issue under softmax VALU work
#pragma unroll
  for (int mt = 0; mt < 2; mt++)
#pragma unroll
    for (int r = 0; r < 4; r++) {
      int h = mt * 16 + quad * 4 + r;
      float v = snk[mt][r];
#pragma unroll
      for (int w = 0; w < 4; w++) v = fmaxf(v, red[w * 32 + h]);
      mh[mt][r] = v;
    }
  float ps[2][4];
#pragma unroll
  for (int mt = 0; mt < 2; mt++)
#pragma unroll
    for (int r = 0; r < 4; r++) {
      float acc = 0.f;
#pragma unroll
      for (int c = 0; c < 4; c++) {
        float e = fast_exp2(sc[c][mt][r] - mh[mt][r]);
        sc[c][mt][r] = e;
        acc += e;
      }
      RED16_SUM(acc);
      ps[mt][r] = acc;
    }
  if (l16 == 0) {
#pragma unroll
    for (int mt = 0; mt < 2; mt++)
#pragma unroll
      for (int r = 0; r < 4; r++)
        red2[wave * 32 + mt * 16 + quad * 4 + r] = ps[mt][r];
  }
  __syncthreads();
  float inv[2][4];
#pragma unroll
  for (int mt = 0; mt < 2; mt++)
#pragma unroll
    for (int r = 0; r < 4; r++) {
      float dd = fast_exp2(snk[mt][r] - mh[mt][r]);
#pragma unroll
      for (int w = 0; w < 4; w++) dd += red2[w * 32 + mt * 16 + quad * 4 + r];
      inv[mt][r] = 1.0f / dd;
    }
  // write P (bf16, unnormalized) to pbuf [head][col] — packed conversions
#pragma unroll
  for (int c = 0; c < 4; c++)
#pragma unroll
    for (int mt = 0; mt < 2; mt++) {
      int col = c * 64 + wave * 16 + l16;
      unsigned short* pb = &pbuf[(mt * 16 + quad * 4) * PB_STRIDE + col];
      unsigned p01 = pk_bf16(sc[c][mt][0], sc[c][mt][1]);
      unsigned p23 = pk_bf16(sc[c][mt][2], sc[c][mt][3]);
      pb[0] = (unsigned short)p01;
      pb[PB_STRIDE] = (unsigned short)(p01 >> 16);
      pb[2 * PB_STRIDE] = (unsigned short)p23;
      pb[3 * PB_STRIDE] = (unsigned short)(p23 >> 16);
    }
  __syncthreads();  // pbuf + V0 visible

  // ---- Phase 3: O = P V, 6 barriers, all V gathers pre-issued ----
  floatx4 oacc[2][2];
#pragma unroll
  for (int mt = 0; mt < 2; mt++)
#pragma unroll
    for (int nt = 0; nt < 2; nt++)
      oacc[mt][nt] = (floatx4){0.f, 0.f, 0.f, 0.f};

  VR v3 = v_load(kvb, tkg, 3, tid);       // in flight across pv0/pv1
  pv_chunk(pbuf, vbuf, 0, wave, quad, l16, oacc);
  __syncthreads();
  v_write(vbuf, v1, tid);
  __syncthreads();

  pv_chunk(pbuf, vbuf, 1, wave, quad, l16, oacc);
  __syncthreads();
  v_write(vbuf, v2, tid);
  __syncthreads();

  pv_chunk(pbuf, vbuf, 2, wave, quad, l16, oacc);
  __syncthreads();
  v_write(vbuf, v3, tid);
  __syncthreads();

  pv_chunk(pbuf, vbuf, 3, wave, quad, l16, oacc);

  // ---- Phase 4: epilogue ----
  {
    float* op = out + (size_t)s * (NH * DH);
#pragma unroll
    for (int mt = 0; mt < 2; mt++)
#pragma unroll
      for (int nt = 0; nt < 2; nt++)
#pragma unroll
        for (int r4 = 0; r4 < 4; r4++) {
          int h = mt * 16 + quad * 4 + r4;
          int d = wave * 32 + nt * 16 + l16;
          op[h * DH + d] = oacc[mt][nt][r4] * inv[mt][r4];
        }
  }
}

extern "C" void kernel_launch(void* const* d_in, const int* in_sizes, int n_in,
                              void* d_out, int out_size, void* d_ws, size_t ws_size,
                              hipStream_t stream) {
  (void)in_sizes; (void)n_in; (void)out_size; (void)ws_size;
  const float* q    = (const float*)d_in[0];
  const float* kv   = (const float*)d_in[1];
  const float* sink = (const float*)d_in[2];
  const int*   topk = (const int*)d_in[3];
  float* out = (float*)d_out;
  unsigned short* kvb = (unsigned short*)d_ws;  // 2 MB bf16 KV

  kv_to_bf16<<<dim3(1024), dim3(256), 0, stream>>>(kv, kvb);
  sparse_attn_kernel<<<dim3(SQ), dim3(256), 0, stream>>>(q, kvb, sink, topk, out);
}

// Round 3
// 129.077 us; speedup vs baseline: 1.0076x; 1.0076x over previous
//
#include <hip/hip_runtime.h>
#include <hip/hip_bf16.h>

#define SQ 2048
#define NH 32
#define DH 128
#define NK 256
#define SCALE 0.08838834764831845f
#define LOG2E 1.4426950408889634f

typedef __attribute__((ext_vector_type(8))) __bf16 bf16x8;
typedef __attribute__((ext_vector_type(4))) float floatx4;

// element strides (u16)
#define KS_STRIDE 136   // K chunk [64][136]; 272 B rows
#define VB_STRIDE 72    // V transposed [d][k_local]; 144 B rows
#define PB_STRIDE 264   // P [head][col]; 528 B rows

// LDS layout (bytes): pbuf 16896 | kv region 18432 (K chunk 17408 / V^T 18432) | red | red2
#define OFF_KV   16896
#define OFF_RED  35328
#define OFF_RED2 35840
#define SMEM_SZ  36352   // 4 blocks/CU

#define SCHED_PIN() __builtin_amdgcn_sched_barrier(0)

__device__ __forceinline__ unsigned pk_bf16(float a, float b) {
  union { __hip_bfloat162 h2; unsigned u; } c;
  c.h2 = __float22bfloat162_rn(make_float2(a, b));
  return c.u;
}

__device__ __forceinline__ float fast_exp2(float x) {
#if __has_builtin(__builtin_amdgcn_exp2f)
  return __builtin_amdgcn_exp2f(x);
#else
  return exp2f(x);
#endif
}

template <int CTRL>
__device__ __forceinline__ float dpp_rot(float x) {
  int i = __builtin_bit_cast(int, x);
  i = __builtin_amdgcn_mov_dpp(i, CTRL, 0xF, 0xF, true);
  return __builtin_bit_cast(float, i);
}
#define RED16_MAX(v) { v = fmaxf(v, dpp_rot<0x121>(v)); v = fmaxf(v, dpp_rot<0x122>(v)); \
                       v = fmaxf(v, dpp_rot<0x124>(v)); v = fmaxf(v, dpp_rot<0x128>(v)); }
#define RED16_SUM(v) { v += dpp_rot<0x121>(v); v += dpp_rot<0x122>(v); \
                       v += dpp_rot<0x124>(v); v += dpp_rot<0x128>(v); }

// ---- pre-pass: kv fp32 [4096][2][128] -> bf16 in d_ws ----
__global__ __launch_bounds__(256) void kv_to_bf16(const float* __restrict__ kv,
                                                  unsigned short* __restrict__ kvb) {
  int i = blockIdx.x * 256 + threadIdx.x;
  float4 f = ((const float4*)kv)[i];
  uint2 o = { pk_bf16(f.x, f.y), pk_bf16(f.z, f.w) };
  ((uint2*)kvb)[i] = o;
}

struct KR { uint4 v[4]; };
struct VR { uint4 a, b, c, d; };

// K chunk gather: thread covers 64 contiguous bytes of one gathered K row.
__device__ __forceinline__ KR k_load(const unsigned short* __restrict__ kvb,
                                     const int* __restrict__ tkg, int c, int tid) {
  int r = tid >> 2, seg = tid & 3;
  int idx = tkg[c * 64 + r];
  const uint4* p = (const uint4*)(kvb + (size_t)idx * 256 + seg * 32);
  KR k;
#pragma unroll
  for (int i = 0; i < 4; i++) k.v[i] = p[i];
  return k;
}

__device__ __forceinline__ void k_write(unsigned short* kvbuf, const KR& k, int tid) {
  int r = tid >> 2, seg = tid & 3;
  uint4* d = (uint4*)&kvbuf[r * KS_STRIDE + seg * 32];
#pragma unroll
  for (int i = 0; i < 4; i++) d[i] = k.v[i];
}

__device__ __forceinline__ VR v_load(const unsigned short* __restrict__ kvb,
                                     const int* __restrict__ tkg, int c, int tid) {
  int rg = tid & 15, dg = tid >> 4;
  int r0 = rg * 4, d0 = dg * 8;
  int4 i4 = *(const int4*)&tkg[c * 64 + r0];
  VR v;
  v.a = *(const uint4*)(kvb + (size_t)i4.x * 256 + 128 + d0);
  v.b = *(const uint4*)(kvb + (size_t)i4.y * 256 + 128 + d0);
  v.c = *(const uint4*)(kvb + (size_t)i4.z * 256 + 128 + d0);
  v.d = *(const uint4*)(kvb + (size_t)i4.w * 256 + 128 + d0);
  return v;
}

__device__ __forceinline__ void v_write(unsigned short* kvbuf, const VR& v, int tid) {
  int rg = tid & 15, dg = tid >> 4;
  int r0 = rg * 4, d0 = dg * 8;
  const unsigned* pa = (const unsigned*)&v.a;
  const unsigned* pb = (const unsigned*)&v.b;
  const unsigned* pc = (const unsigned*)&v.c;
  const unsigned* pd = (const unsigned*)&v.d;
#pragma unroll
  for (int w = 0; w < 4; w++) {
    unsigned lo01 = __builtin_amdgcn_perm(pb[w], pa[w], 0x05040100u);
    unsigned lo23 = __builtin_amdgcn_perm(pd[w], pc[w], 0x05040100u);
    unsigned hi01 = __builtin_amdgcn_perm(pb[w], pa[w], 0x07060302u);
    unsigned hi23 = __builtin_amdgcn_perm(pd[w], pc[w], 0x07060302u);
    uint2 lo = { lo01, lo23 }, hi = { hi01, hi23 };
    *(uint2*)&kvbuf[(d0 + 2 * w) * VB_STRIDE + r0] = lo;
    *(uint2*)&kvbuf[(d0 + 2 * w + 1) * VB_STRIDE + r0] = hi;
  }
}

// GEMM1 from LDS-staged K (ds_read latency is short and compiler-pipelined)
__device__ __forceinline__ void gemm1(const unsigned short* kvbuf,
                                      const bf16x8 af[2][4], int nrow, int quad,
                                      floatx4& a0, floatx4& a1) {
  a0 = (floatx4){0.f, 0.f, 0.f, 0.f};
  a1 = (floatx4){0.f, 0.f, 0.f, 0.f};
  __builtin_amdgcn_s_setprio(1);
#pragma unroll
  for (int ks = 0; ks < 4; ks++) {
    bf16x8 b = *(const bf16x8*)&kvbuf[nrow * KS_STRIDE + ks * 32 + quad * 8];
    a0 = __builtin_amdgcn_mfma_f32_16x16x32_bf16(af[0][ks], b, a0, 0, 0, 0);
    a1 = __builtin_amdgcn_mfma_f32_16x16x32_bf16(af[1][ks], b, a1, 0, 0, 0);
  }
  __builtin_amdgcn_s_setprio(0);
}

__device__ __forceinline__ void pv_chunk(const unsigned short* pbuf,
                                         const unsigned short* kvbuf, int c,
                                         int wave, int quad, int l16,
                                         floatx4 oacc[2][2]) {
  __builtin_amdgcn_s_setprio(1);
#pragma unroll
  for (int ks = 0; ks < 2; ks++) {
    int kof = c * 64 + ks * 32 + quad * 8;
    bf16x8 a0 = *(const bf16x8*)&pbuf[l16 * PB_STRIDE + kof];
    bf16x8 a1 = *(const bf16x8*)&pbuf[(16 + l16) * PB_STRIDE + kof];
    int kl = ks * 32 + quad * 8;
    bf16x8 b0 = *(const bf16x8*)&kvbuf[(wave * 32 + l16) * VB_STRIDE + kl];
    bf16x8 b1 = *(const bf16x8*)&kvbuf[(wave * 32 + 16 + l16) * VB_STRIDE + kl];
    oacc[0][0] = __builtin_amdgcn_mfma_f32_16x16x32_bf16(a0, b0, oacc[0][0], 0, 0, 0);
    oacc[0][1] = __builtin_amdgcn_mfma_f32_16x16x32_bf16(a0, b1, oacc[0][1], 0, 0, 0);
    oacc[1][0] = __builtin_amdgcn_mfma_f32_16x16x32_bf16(a1, b0, oacc[1][0], 0, 0, 0);
    oacc[1][1] = __builtin_amdgcn_mfma_f32_16x16x32_bf16(a1, b1, oacc[1][1], 0, 0, 0);
  }
  __builtin_amdgcn_s_setprio(0);
}

__global__ __launch_bounds__(256, 4) void sparse_attn_kernel(
    const float* __restrict__ q, const unsigned short* __restrict__ kvb,
    const float* __restrict__ sink, const int* __restrict__ topk,
    float* __restrict__ out) {
  __shared__ __align__(16) char smem[SMEM_SZ];
  unsigned short* pbuf  = (unsigned short*)smem;             // P [32][264]
  unsigned short* kvbuf = (unsigned short*)(smem + OFF_KV);  // K chunk / V^T chunk
  float* red  = (float*)(smem + OFF_RED);
  float* red2 = (float*)(smem + OFF_RED2);

  const int tid = threadIdx.x;
  const int s = blockIdx.x;
  const int wave = tid >> 6;
  const int lane = tid & 63;
  const int quad = lane >> 4;
  const int l16 = lane & 15;
  const int* tkg = topk + (size_t)s * NK;

  // ---- Phase 0: issue K0 gather, Q loads, K1+K2 prefetch; convert Q under them ----
  // K0: global -> regs (per-thread 64 B of a gathered row)
  KR k0 = k_load(kvb, tkg, 0, tid);
  SCHED_PIN();

  const float QSC = SCALE * LOG2E;
  const float* qp = q + (size_t)s * (NH * DH);
  float4 qf[2][4][2];
#pragma unroll
  for (int mt = 0; mt < 2; mt++)
#pragma unroll
    for (int ks = 0; ks < 4; ks++) {
      const float* base = qp + (mt * 16 + l16) * DH + ks * 32 + quad * 8;
      qf[mt][ks][0] = ((const float4*)base)[0];
      qf[mt][ks][1] = ((const float4*)base)[1];
    }
  KR k1 = k_load(kvb, tkg, 1, tid);   // 2-deep K prefetch
  KR k2 = k_load(kvb, tkg, 2, tid);
  SCHED_PIN();

  float snk[2][4];
#pragma unroll
  for (int mt = 0; mt < 2; mt++)
#pragma unroll
    for (int r = 0; r < 4; r++)
      snk[mt][r] = sink[mt * 16 + quad * 4 + r] * LOG2E;

  // Q -> bf16 A-frags (VALU, overlaps in-flight gathers)
  bf16x8 afrag[2][4];
#pragma unroll
  for (int mt = 0; mt < 2; mt++)
#pragma unroll
    for (int ks = 0; ks < 4; ks++) {
      float4 f0 = qf[mt][ks][0], f1 = qf[mt][ks][1];
      uint4 u = { pk_bf16(f0.x * QSC, f0.y * QSC), pk_bf16(f0.z * QSC, f0.w * QSC),
                  pk_bf16(f1.x * QSC, f1.y * QSC), pk_bf16(f1.z * QSC, f1.w * QSC) };
      afrag[mt][ks] = __builtin_bit_cast(bf16x8, u);
    }
  k_write(kvbuf, k0, tid);   // K0 regs -> LDS
  __syncthreads();           // K0 visible

  const int nrow = wave * 16 + l16;

  // ---- Phase 1: GEMM1, LDS single-buffer with 2-deep register pipeline ----
  floatx4 sc[4][2];
  gemm1(kvbuf, afrag, nrow, quad, sc[0][0], sc[0][1]);
  __syncthreads();                 // K0 reads done
  k_write(kvbuf, k1, tid);
  KR k3 = k_load(kvb, tkg, 3, tid);
  SCHED_PIN();
  __syncthreads();                 // K1 visible

  gemm1(kvbuf, afrag, nrow, quad, sc[1][0], sc[1][1]);
  __syncthreads();
  k_write(kvbuf, k2, tid);
  VR v0 = v_load(kvb, tkg, 0, tid);
  SCHED_PIN();
  __syncthreads();

  gemm1(kvbuf, afrag, nrow, quad, sc[2][0], sc[2][1]);
  __syncthreads();
  k_write(kvbuf, k3, tid);
  VR v1 = v_load(kvb, tkg, 1, tid);   // consumed after pv0: ~3 phases of cover
  SCHED_PIN();
  __syncthreads();

  gemm1(kvbuf, afrag, nrow, quad, sc[3][0], sc[3][1]);
  __syncthreads();                 // K3 reads done; K region now dead
  v_write(kvbuf, v0, tid);         // V0 -> LDS transposed (settles under softmax)

  // ---- Phase 2: softmax with sink (scores in exp2 domain) ----
  float mh[2][4];
#pragma unroll
  for (int mt = 0; mt < 2; mt++)
#pragma unroll
    for (int r = 0; r < 4; r++) {
      float v = fmaxf(fmaxf(sc[0][mt][r], sc[1][mt][r]),
                      fmaxf(sc[2][mt][r], sc[3][mt][r]));
      RED16_MAX(v);
      mh[mt][r] = v;
    }
  if (l16 == 0) {
#pragma unroll
    for (int mt = 0; mt < 2; mt++)
#pragma unroll
      for (int r = 0; r < 4; r++)
        red[wave * 32 + mt * 16 + quad * 4 + r] = mh[mt][r];
  }
  __syncthreads();  // red visible (also covers V0 writes; pbuf barrier re-covers)
  VR v2 = v_load(kvb, tkg, 2, tid);   // issue under softmax VALU work
  SCHED_PIN();
#pragma unroll
  for (int mt = 0; mt < 2; mt++)
#pragma unroll
    for (int r = 0; r < 4; r++) {
      int h = mt * 16 + quad * 4 + r;
      float v = snk[mt][r];
#pragma unroll
      for (int w = 0; w < 4; w++) v = fmaxf(v, red[w * 32 + h]);
      mh[mt][r] = v;
    }
  float ps[2][4];
#pragma unroll
  for (int mt = 0; mt < 2; mt++)
#pragma unroll
    for (int r = 0; r < 4; r++) {
      float acc = 0.f;
#pragma unroll
      for (int c = 0; c < 4; c++) {
        float e = fast_exp2(sc[c][mt][r] - mh[mt][r]);
        sc[c][mt][r] = e;
        acc += e;
      }
      RED16_SUM(acc);
      ps[mt][r] = acc;
    }
  if (l16 == 0) {
#pragma unroll
    for (int mt = 0; mt < 2; mt++)
#pragma unroll
      for (int r = 0; r < 4; r++)
        red2[wave * 32 + mt * 16 + quad * 4 + r] = ps[mt][r];
  }
  __syncthreads();
  float inv[2][4];
#pragma unroll
  for (int mt = 0; mt < 2; mt++)
#pragma unroll
    for (int r = 0; r < 4; r++) {
      float dd = fast_exp2(snk[mt][r] - mh[mt][r]);
#pragma unroll
      for (int w = 0; w < 4; w++) dd += red2[w * 32 + mt * 16 + quad * 4 + r];
      inv[mt][r] = 1.0f / dd;
    }
  // write P (bf16, unnormalized) to pbuf [head][col]
#pragma unroll
  for (int c = 0; c < 4; c++)
#pragma unroll
    for (int mt = 0; mt < 2; mt++) {
      int col = c * 64 + wave * 16 + l16;
      unsigned short* pb = &pbuf[(mt * 16 + quad * 4) * PB_STRIDE + col];
      unsigned p01 = pk_bf16(sc[c][mt][0], sc[c][mt][1]);
      unsigned p23 = pk_bf16(sc[c][mt][2], sc[c][mt][3]);
      pb[0] = (unsigned short)p01;
      pb[PB_STRIDE] = (unsigned short)(p01 >> 16);
      pb[2 * PB_STRIDE] = (unsigned short)p23;
      pb[3 * PB_STRIDE] = (unsigned short)(p23 >> 16);
    }
  __syncthreads();  // pbuf + V0 visible

  // ---- Phase 3: O = P V with register-prefetch pipeline ----
  floatx4 oacc[2][2];
#pragma unroll
  for (int mt = 0; mt < 2; mt++)
#pragma unroll
    for (int nt = 0; nt < 2; nt++)
      oacc[mt][nt] = (floatx4){0.f, 0.f, 0.f, 0.f};

  VR v3 = v_load(kvb, tkg, 3, tid);   // in flight across pv0/pv1
  SCHED_PIN();
  pv_chunk(pbuf, kvbuf, 0, wave, quad, l16, oacc);
  __syncthreads();
  v_write(kvbuf, v1, tid);
  __syncthreads();

  pv_chunk(pbuf, kvbuf, 1, wave, quad, l16, oacc);
  __syncthreads();
  v_write(kvbuf, v2, tid);
  __syncthreads();

  pv_chunk(pbuf, kvbuf, 2, wave, quad, l16, oacc);
  __syncthreads();
  v_write(kvbuf, v3, tid);
  __syncthreads();

  pv_chunk(pbuf, kvbuf, 3, wave, quad, l16, oacc);

  // ---- Phase 4: epilogue ----
  {
    float* op = out + (size_t)s * (NH * DH);
#pragma unroll
    for (int mt = 0; mt < 2; mt++)
#pragma unroll
      for (int nt = 0; nt < 2; nt++)
#pragma unroll
        for (int r4 = 0; r4 < 4; r4++) {
          int h = mt * 16 + quad * 4 + r4;
          int d = wave * 32 + nt * 16 + l16;
          op[h * DH + d] = oacc[mt][nt][r4] * inv[mt][r4];
        }
  }
}

extern "C" void kernel_launch(void* const* d_in, const int* in_sizes, int n_in,
                              void* d_out, int out_size, void* d_ws, size_t ws_size,
                              hipStream_t stream) {
  (void)in_sizes; (void)n_in; (void)out_size; (void)ws_size;
  const float* q    = (const float*)d_in[0];
  const float* kv   = (const float*)d_in[1];
  const float* sink = (const float*)d_in[2];
  const int*   topk = (const int*)d_in[3];
  float* out = (float*)d_out;
  unsigned short* kvb = (unsigned short*)d_ws;  // 2 MB bf16 KV

  kv_to_bf16<<<dim3(1024), dim3(256), 0, stream>>>(kv, kvb);
  sparse_attn_kernel<<<dim3(SQ), dim3(256), 0, stream>>>(q, kvb, sink, topk, out);
}

// Round 4
// 117.619 us; speedup vs baseline: 1.1058x; 1.0974x over previous
//
#include <hip/hip_runtime.h>
#include <hip/hip_bf16.h>

#define SQ 2048
#define NH 32
#define DH 128
#define NK 256
#define SCALE 0.08838834764831845f
#define LOG2E 1.4426950408889634f

typedef __attribute__((ext_vector_type(8))) __bf16 bf16x8;
typedef __attribute__((ext_vector_type(4))) float floatx4;

// element strides (u16)
#define QS_STRIDE 136   // Q staged rows, 272 B (16B-aligned, 2-way banks = free)
#define KS_STRIDE 136   // K chunk [64][136]; 272 B rows
#define VB_STRIDE 72    // V transposed [d][k_local]; 144 B rows
#define PB_STRIDE 264   // P [head][col]; 528 B rows

// LDS (bytes): pbuf 16896 | dbuf0 18432 | dbuf1 18432 ; red/red2 in dbuf1 tail
// (K uses only [64][136]=17408 of each 18432 buffer; the 1 KB tail of dbuf1
//  holds the softmax stats, dead before any V write lands there)
#define OFF_DB0  16896
#define DBSZ     18432
#define OFF_DB1  (OFF_DB0 + DBSZ)          // 35328
#define OFF_RED  (OFF_DB1 + 17408)         // 52736: 128 floats (m_w)
#define OFF_RED2 (OFF_RED + 512)           // 53248: 128 floats (p_w)
#define SMEM_SZ  53760                     // x3 = 161280 <= 163840 -> 3 blocks/CU

#define SCHED_PIN() __builtin_amdgcn_sched_barrier(0)

__device__ __forceinline__ unsigned pk_bf16(float a, float b) {
  union { __hip_bfloat162 h2; unsigned u; } c;
  c.h2 = __float22bfloat162_rn(make_float2(a, b));
  return c.u;
}

__device__ __forceinline__ float fast_exp2(float x) {
#if __has_builtin(__builtin_amdgcn_exp2f)
  return __builtin_amdgcn_exp2f(x);
#else
  return exp2f(x);
#endif
}

template <int CTRL>
__device__ __forceinline__ float dpp_rot(float x) {
  int i = __builtin_bit_cast(int, x);
  i = __builtin_amdgcn_mov_dpp(i, CTRL, 0xF, 0xF, true);
  return __builtin_bit_cast(float, i);
}
#define RED16_MAX(v) { v = fmaxf(v, dpp_rot<0x121>(v)); v = fmaxf(v, dpp_rot<0x122>(v)); \
                       v = fmaxf(v, dpp_rot<0x124>(v)); v = fmaxf(v, dpp_rot<0x128>(v)); }
#define RED16_SUM(v) { v += dpp_rot<0x121>(v); v += dpp_rot<0x122>(v); \
                       v += dpp_rot<0x124>(v); v += dpp_rot<0x128>(v); }

// ---- pre-pass: kv fp32 [4096][2][128] -> bf16 in d_ws ----
__global__ __launch_bounds__(256) void kv_to_bf16(const float* __restrict__ kv,
                                                  unsigned short* __restrict__ kvb) {
  int i = blockIdx.x * 256 + threadIdx.x;
  float4 f = ((const float4*)kv)[i];
  uint2 o = { pk_bf16(f.x, f.y), pk_bf16(f.z, f.w) };
  ((uint2*)kvb)[i] = o;
}

struct KR { uint4 v[4]; };
struct VR { uint4 a, b, c, d; };

__device__ __forceinline__ KR k_load(const unsigned short* __restrict__ kvb,
                                     const int* __restrict__ tkg, int c, int tid) {
  int r = tid >> 2, seg = tid & 3;
  int idx = tkg[c * 64 + r];
  const uint4* p = (const uint4*)(kvb + (size_t)idx * 256 + seg * 32);
  KR k;
#pragma unroll
  for (int i = 0; i < 4; i++) k.v[i] = p[i];
  return k;
}

__device__ __forceinline__ void k_write(unsigned short* kbuf, const KR& k, int tid) {
  int r = tid >> 2, seg = tid & 3;
  uint4* d = (uint4*)&kbuf[r * KS_STRIDE + seg * 32];
#pragma unroll
  for (int i = 0; i < 4; i++) d[i] = k.v[i];
}

__device__ __forceinline__ VR v_load(const unsigned short* __restrict__ kvb,
                                     const int* __restrict__ tkg, int c, int tid) {
  int rg = tid & 15, dg = tid >> 4;
  int r0 = rg * 4, d0 = dg * 8;
  int4 i4 = *(const int4*)&tkg[c * 64 + r0];
  VR v;
  v.a = *(const uint4*)(kvb + (size_t)i4.x * 256 + 128 + d0);
  v.b = *(const uint4*)(kvb + (size_t)i4.y * 256 + 128 + d0);
  v.c = *(const uint4*)(kvb + (size_t)i4.z * 256 + 128 + d0);
  v.d = *(const uint4*)(kvb + (size_t)i4.w * 256 + 128 + d0);
  return v;
}

__device__ __forceinline__ void v_write(unsigned short* vbuf, const VR& v, int tid) {
  int rg = tid & 15, dg = tid >> 4;
  int r0 = rg * 4, d0 = dg * 8;
  const unsigned* pa = (const unsigned*)&v.a;
  const unsigned* pb = (const unsigned*)&v.b;
  const unsigned* pc = (const unsigned*)&v.c;
  const unsigned* pd = (const unsigned*)&v.d;
#pragma unroll
  for (int w = 0; w < 4; w++) {
    unsigned lo01 = __builtin_amdgcn_perm(pb[w], pa[w], 0x05040100u);
    unsigned lo23 = __builtin_amdgcn_perm(pd[w], pc[w], 0x05040100u);
    unsigned hi01 = __builtin_amdgcn_perm(pb[w], pa[w], 0x07060302u);
    unsigned hi23 = __builtin_amdgcn_perm(pd[w], pc[w], 0x07060302u);
    uint2 lo = { lo01, lo23 }, hi = { hi01, hi23 };
    *(uint2*)&vbuf[(d0 + 2 * w) * VB_STRIDE + r0] = lo;
    *(uint2*)&vbuf[(d0 + 2 * w + 1) * VB_STRIDE + r0] = hi;
  }
}

__device__ __forceinline__ void gemm1(const unsigned short* kbuf,
                                      const bf16x8 af[2][4], int nrow, int quad,
                                      floatx4& a0, floatx4& a1) {
  a0 = (floatx4){0.f, 0.f, 0.f, 0.f};
  a1 = (floatx4){0.f, 0.f, 0.f, 0.f};
  __builtin_amdgcn_s_setprio(1);
#pragma unroll
  for (int ks = 0; ks < 4; ks++) {
    bf16x8 b = *(const bf16x8*)&kbuf[nrow * KS_STRIDE + ks * 32 + quad * 8];
    a0 = __builtin_amdgcn_mfma_f32_16x16x32_bf16(af[0][ks], b, a0, 0, 0, 0);
    a1 = __builtin_amdgcn_mfma_f32_16x16x32_bf16(af[1][ks], b, a1, 0, 0, 0);
  }
  __builtin_amdgcn_s_setprio(0);
}

__device__ __forceinline__ void pv_chunk(const unsigned short* pbuf,
                                         const unsigned short* vbuf, int c,
                                         int wave, int quad, int l16,
                                         floatx4 oacc[2][2]) {
  __builtin_amdgcn_s_setprio(1);
#pragma unroll
  for (int ks = 0; ks < 2; ks++) {
    int kof = c * 64 + ks * 32 + quad * 8;
    bf16x8 a0 = *(const bf16x8*)&pbuf[l16 * PB_STRIDE + kof];
    bf16x8 a1 = *(const bf16x8*)&pbuf[(16 + l16) * PB_STRIDE + kof];
    int kl = ks * 32 + quad * 8;
    bf16x8 b0 = *(const bf16x8*)&vbuf[(wave * 32 + l16) * VB_STRIDE + kl];
    bf16x8 b1 = *(const bf16x8*)&vbuf[(wave * 32 + 16 + l16) * VB_STRIDE + kl];
    oacc[0][0] = __builtin_amdgcn_mfma_f32_16x16x32_bf16(a0, b0, oacc[0][0], 0, 0, 0);
    oacc[0][1] = __builtin_amdgcn_mfma_f32_16x16x32_bf16(a0, b1, oacc[0][1], 0, 0, 0);
    oacc[1][0] = __builtin_amdgcn_mfma_f32_16x16x32_bf16(a1, b0, oacc[1][0], 0, 0, 0);
    oacc[1][1] = __builtin_amdgcn_mfma_f32_16x16x32_bf16(a1, b1, oacc[1][1], 0, 0, 0);
  }
  __builtin_amdgcn_s_setprio(0);
}

__global__ __launch_bounds__(256, 3) void sparse_attn_kernel(
    const float* __restrict__ q, const unsigned short* __restrict__ kvb,
    const float* __restrict__ sink, const int* __restrict__ topk,
    float* __restrict__ out) {
  __shared__ __align__(16) char smem[SMEM_SZ];
  unsigned short* pbuf = (unsigned short*)smem;              // P [32][264]; qs overlay ph0
  unsigned short* qs   = (unsigned short*)smem;
  unsigned short* db0  = (unsigned short*)(smem + OFF_DB0);  // K/V^T double buffer
  unsigned short* db1  = (unsigned short*)(smem + OFF_DB1);
  float* red  = (float*)(smem + OFF_RED);    // per-wave local max  m_w[wave][head]
  float* red2 = (float*)(smem + OFF_RED2);   // per-wave local sum  p_w[wave][head]

  const int tid = threadIdx.x;
  const int s = blockIdx.x;
  const int wave = tid >> 6;
  const int lane = tid & 63;
  const int quad = lane >> 4;
  const int l16 = lane & 15;
  const int* tkg = topk + (size_t)s * NK;
  unsigned short* dbuf[2] = { db0, db1 };

  // ---- Phase 0: K0 -> db0 (through regs), k1 prefetch, Q staged+scaled ----
  {
    int r = tid >> 2, seg = tid & 3;
    int idx = tkg[r];
    const uint4* p = (const uint4*)(kvb + (size_t)idx * 256 + seg * 32);
    uint4* d = (uint4*)&db0[r * KS_STRIDE + seg * 32];
#pragma unroll
    for (int i = 0; i < 4; i++) d[i] = p[i];
  }
  KR k1 = k_load(kvb, tkg, 1, tid);
  SCHED_PIN();

  float snk[2][4];
#pragma unroll
  for (int mt = 0; mt < 2; mt++)
#pragma unroll
    for (int r = 0; r < 4; r++)
      snk[mt][r] = sink[mt * 16 + quad * 4 + r] * LOG2E;

  {  // Q stage, pre-scaled by SCALE*log2(e): softmax runs in exp2 domain
    const float QSC = SCALE * LOG2E;
    const float* qp = q + (size_t)s * (NH * DH);
    int h = tid >> 3, d0 = (tid & 7) * 16;
    const float4* src = (const float4*)(qp + h * DH + d0);
    float4 f0 = src[0], f1 = src[1], f2 = src[2], f3 = src[3];
    uint4 o0 = { pk_bf16(f0.x * QSC, f0.y * QSC), pk_bf16(f0.z * QSC, f0.w * QSC),
                 pk_bf16(f1.x * QSC, f1.y * QSC), pk_bf16(f1.z * QSC, f1.w * QSC) };
    uint4 o1 = { pk_bf16(f2.x * QSC, f2.y * QSC), pk_bf16(f2.z * QSC, f2.w * QSC),
                 pk_bf16(f3.x * QSC, f3.y * QSC), pk_bf16(f3.z * QSC, f3.w * QSC) };
    *(uint4*)&qs[h * QS_STRIDE + d0] = o0;
    *(uint4*)&qs[h * QS_STRIDE + d0 + 8] = o1;
  }
  __syncthreads();  // K0 + qs visible

  // Hoist Q A-fragments from LDS (qs dead afterwards; pbuf reuses the space)
  bf16x8 afrag[2][4];
#pragma unroll
  for (int mt = 0; mt < 2; mt++)
#pragma unroll
    for (int ks = 0; ks < 4; ks++)
      afrag[mt][ks] =
          *(const bf16x8*)&qs[(mt * 16 + l16) * QS_STRIDE + ks * 32 + quad * 8];

  const int nrow = wave * 16 + l16;

  // ---- Phase 1: GEMM1, double-buffered K: ONE barrier per chunk ----
  floatx4 sc[4][2];
  // c0: read db0 | write k1->db1 | issue k2
  KR k2 = k_load(kvb, tkg, 2, tid);
  SCHED_PIN();
  gemm1(dbuf[0], afrag, nrow, quad, sc[0][0], sc[0][1]);
  k_write(dbuf[1], k1, tid);
  __syncthreads();  // K1 visible; db0 reads done

  // c1: read db1 | write k2->db0 | issue k3
  KR k3 = k_load(kvb, tkg, 3, tid);
  SCHED_PIN();
  gemm1(dbuf[1], afrag, nrow, quad, sc[1][0], sc[1][1]);
  k_write(dbuf[0], k2, tid);
  __syncthreads();

  // c2: read db0 | write k3->db1 | issue v0
  VR v0 = v_load(kvb, tkg, 0, tid);
  SCHED_PIN();
  gemm1(dbuf[0], afrag, nrow, quad, sc[2][0], sc[2][1]);
  k_write(dbuf[1], k3, tid);
  __syncthreads();

  // c3: read db1 | write v0->db0 (V^T) | issue v1; NO barrier (stats barrier covers)
  VR v1 = v_load(kvb, tkg, 1, tid);
  SCHED_PIN();
  gemm1(dbuf[1], afrag, nrow, quad, sc[3][0], sc[3][1]);
  v_write(dbuf[0], v0, tid);

  // ---- Phase 2: softmax, flash-style single stats exchange ----
  // local max over this wave's 64 keys
  float mh[2][4];
#pragma unroll
  for (int mt = 0; mt < 2; mt++)
#pragma unroll
    for (int r = 0; r < 4; r++) {
      float v = fmaxf(fmaxf(sc[0][mt][r], sc[1][mt][r]),
                      fmaxf(sc[2][mt][r], sc[3][mt][r]));
      RED16_MAX(v);
      mh[mt][r] = v;
    }
  // local exp + partial sums (pre-barrier VALU work)
  float ps[2][4];
#pragma unroll
  for (int mt = 0; mt < 2; mt++)
#pragma unroll
    for (int r = 0; r < 4; r++) {
      float acc = 0.f;
#pragma unroll
      for (int c = 0; c < 4; c++) {
        float e = fast_exp2(sc[c][mt][r] - mh[mt][r]);
        sc[c][mt][r] = e;
        acc += e;
      }
      RED16_SUM(acc);
      ps[mt][r] = acc;
    }
  if (l16 == 0) {
#pragma unroll
    for (int mt = 0; mt < 2; mt++)
#pragma unroll
      for (int r = 0; r < 4; r++) {
        red[wave * 32 + mt * 16 + quad * 4 + r]  = mh[mt][r];
        red2[wave * 32 + mt * 16 + quad * 4 + r] = ps[mt][r];
      }
  }
  __syncthreads();  // stats visible (also covers c3's db1 reads)
  VR v2 = v_load(kvb, tkg, 2, tid);  // issue under the stats math
  SCHED_PIN();
  float inv[2][4], sf[2][4];
#pragma unroll
  for (int mt = 0; mt < 2; mt++)
#pragma unroll
    for (int r = 0; r < 4; r++) {
      int h = mt * 16 + quad * 4 + r;
      float M = snk[mt][r];
#pragma unroll
      for (int w = 0; w < 4; w++) M = fmaxf(M, red[w * 32 + h]);
      float dd = fast_exp2(snk[mt][r] - M);
#pragma unroll
      for (int w = 0; w < 4; w++)
        dd += red2[w * 32 + h] * fast_exp2(red[w * 32 + h] - M);
      inv[mt][r] = 1.0f / dd;
      sf[mt][r] = fast_exp2(mh[mt][r] - M);  // rescale local->global
    }
  // write P = e_local * sf (bf16, unnormalized) to pbuf [head][col]
#pragma unroll
  for (int c = 0; c < 4; c++)
#pragma unroll
    for (int mt = 0; mt < 2; mt++) {
      int col = c * 64 + wave * 16 + l16;
      unsigned short* pb = &pbuf[(mt * 16 + quad * 4) * PB_STRIDE + col];
      unsigned p01 = pk_bf16(sc[c][mt][0] * sf[mt][0], sc[c][mt][1] * sf[mt][1]);
      unsigned p23 = pk_bf16(sc[c][mt][2] * sf[mt][2], sc[c][mt][3] * sf[mt][3]);
      pb[0] = (unsigned short)p01;
      pb[PB_STRIDE] = (unsigned short)(p01 >> 16);
      pb[2 * PB_STRIDE] = (unsigned short)p23;
      pb[3 * PB_STRIDE] = (unsigned short)(p23 >> 16);
    }
  __syncthreads();  // pbuf + V0(db0) visible; red/red2 dead from here

  // ---- Phase 3: O = P V, double-buffered V^T: ONE barrier per chunk ----
  floatx4 oacc[2][2];
#pragma unroll
  for (int mt = 0; mt < 2; mt++)
#pragma unroll
    for (int nt = 0; nt < 2; nt++)
      oacc[mt][nt] = (floatx4){0.f, 0.f, 0.f, 0.f};

  // pv0: read db0 | write v1->db1 | issue v3
  VR v3 = v_load(kvb, tkg, 3, tid);
  SCHED_PIN();
  pv_chunk(pbuf, dbuf[0], 0, wave, quad, l16, oacc);
  v_write(dbuf[1], v1, tid);  // overwrites red/red2 tail: dead
  __syncthreads();

  // pv1: read db1 | write v2->db0
  pv_chunk(pbuf, dbuf[1], 1, wave, quad, l16, oacc);
  v_write(dbuf[0], v2, tid);
  __syncthreads();

  // pv2: read db0 | write v3->db1
  pv_chunk(pbuf, dbuf[0], 2, wave, quad, l16, oacc);
  v_write(dbuf[1], v3, tid);
  __syncthreads();

  // pv3: read db1
  pv_chunk(pbuf, dbuf[1], 3, wave, quad, l16, oacc);

  // ---- Phase 4: epilogue ----
  {
    float* op = out + (size_t)s * (NH * DH);
#pragma unroll
    for (int mt = 0; mt < 2; mt++)
#pragma unroll
      for (int nt = 0; nt < 2; nt++)
#pragma unroll
        for (int r4 = 0; r4 < 4; r4++) {
          int h = mt * 16 + quad * 4 + r4;
          int d = wave * 32 + nt * 16 + l16;
          op[h * DH + d] = oacc[mt][nt][r4] * inv[mt][r4];
        }
  }
}

extern "C" void kernel_launch(void* const* d_in, const int* in_sizes, int n_in,
                              void* d_out, int out_size, void* d_ws, size_t ws_size,
                              hipStream_t stream) {
  (void)in_sizes; (void)n_in; (void)out_size; (void)ws_size;
  const float* q    = (const float*)d_in[0];
  const float* kv   = (const float*)d_in[1];
  const float* sink = (const float*)d_in[2];
  const int*   topk = (const int*)d_in[3];
  float* out = (float*)d_out;
  unsigned short* kvb = (unsigned short*)d_ws;  // 2 MB bf16 KV

  kv_to_bf16<<<dim3(1024), dim3(256), 0, stream>>>(kv, kvb);
  sparse_attn_kernel<<<dim3(SQ), dim3(256), 0, stream>>>(q, kvb, sink, topk, out);
}